// Round 2
// baseline (4016.651 us; speedup 1.0000x reference)
//
#include <hip/hip_runtime.h>

typedef short short8 __attribute__((ext_vector_type(8)));
typedef float f32x4 __attribute__((ext_vector_type(4)));
typedef unsigned int uint;

#define C_IN  128
#define H_IN  112
#define W_IN  112
#define K_OUT 256
#define H_OUTD 110
#define W_OUTD 110
#define NBATCH 32

// xT layout: [n][ph(2)][h(112)][w(112)][64] bf16, swizzled within 64: pos = (c&63) ^ ((w&7)<<3)
#define XT_ELEMS (NBATCH*2*H_IN*W_IN*64)   // 51,380,224
#define F_ELEMS  (9*K_OUT*C_IN)            // 294,912

__device__ __forceinline__ unsigned short f2bf(float f) {
  uint u = __float_as_uint(f);
  u += 0x7fffu + ((u >> 16) & 1u);   // RNE
  return (unsigned short)(u >> 16);
}

// ---------------- prep: x (NCHW f32) -> xT (swizzled bf16) ----------------
__global__ __launch_bounds__(256) void xpose_kernel(const float* __restrict__ x,
                                                    unsigned short* __restrict__ xT) {
  __shared__ unsigned short sm[H_IN * 128];   // [w][c''] 28,672 B
  const int n = blockIdx.y;
  const int h = blockIdx.x;
  const int tid = threadIdx.x;
  for (int it = 0; it < 28; ++it) {
    int idx = it*256 + tid;            // 0..7167  (64 c-pairs x 112 w)
    int w  = idx % 112;
    int cp = idx / 112;                // 0..63
    int c0 = cp*2;
    const float* px = x + ((size_t)(n*C_IN + c0)*H_IN + h)*W_IN + w;
    float f0 = px[0];
    float f1 = px[H_IN*W_IN];
    uint key  = ((uint)w & 7u) << 3;
    uint cpos = ((uint)c0 & 64u) | (((uint)c0 & 63u) ^ key);
    uint v = (uint)f2bf(f0) | ((uint)f2bf(f1) << 16);
    *(uint*)&sm[w*128 + cpos] = v;
  }
  __syncthreads();
  for (int it = 0; it < 7; ++it) {
    int idx = it*256 + tid;            // 0..1791
    int ph  = idx / 896;
    int rem = idx - ph*896;
    int w   = rem >> 3;
    int ck  = rem & 7;
    uint4 v = *(const uint4*)&sm[w*128 + ph*64 + ck*8];
    int off = (((n*2 + ph)*H_IN + h)*W_IN + w)*64 + ck*8;
    *(uint4*)&xT[off] = v;
  }
}

// ---------------- prep: filt (OIHW f32) -> F[rs][k][c] bf16 ----------------
__global__ __launch_bounds__(256) void fprep_kernel(const float* __restrict__ ft,
                                                    unsigned short* __restrict__ F) {
  int idx = blockIdx.x*256 + threadIdx.x;   // < 294912
  int rs  = idx >> 15;
  int rem = idx & 32767;
  int k   = rem >> 7;
  int c   = rem & 127;
  F[idx] = f2bf(ft[(k*C_IN + c)*9 + rs]);
}

// ---------------- main implicit-GEMM conv ----------------
// block: 512 thr (8 waves, 4M x 2N), output tile = 256 K_out x (8h x 16w) pixels
// LDS: halo tile 10h x 18w x 64c bf16 = 23,040 B -> 4 blocks/CU (wave-capped)
__global__ __launch_bounds__(512, 8) void conv_gemm(const unsigned short* __restrict__ xT,
                                                    const unsigned short* __restrict__ F,
                                                    float* __restrict__ out) {
  __shared__ unsigned short sm[10*18*64];   // 23,040 B
  const int tile = blockIdx.x;              // 0..97 (14 h-tiles x 7 w-tiles)
  const int n    = blockIdx.y;
  const int tid  = threadIdx.x;
  const int lane = tid & 63;
  const int wid  = tid >> 6;
  const int wm   = wid & 3;                 // M quadrant (64 k each)
  const int wn   = wid >> 2;                // N half (4 h-rows each)
  const int l15  = lane & 15;
  const int lhi  = lane >> 4;               // 0..3
  const int th   = tile / 7;
  const int tw   = tile - th*7;
  const int h0   = th*8;
  const int w0   = tw*16;

  int arow[4];
  #pragma unroll
  for (int mt = 0; mt < 4; ++mt)
    arow[mt] = (wm*64 + mt*16 + l15)*128;
  int browb[4];
  #pragma unroll
  for (int nt = 0; nt < 4; ++nt)
    browb[nt] = ((wn*4 + nt)*18 + l15)*64;   // (hh row)*18 + ww(=l15), in 64-short units
  const int wkey = w0 + l15;

  f32x4 acc[4][4];
  #pragma unroll
  for (int mt = 0; mt < 4; ++mt)
    #pragma unroll
    for (int nt = 0; nt < 4; ++nt)
      acc[mt][nt] = (f32x4){0.f, 0.f, 0.f, 0.f};

  for (int ph = 0; ph < 2; ++ph) {
    if (ph) __syncthreads();
    // stage halo tile: 180 chunks of 128B, linear LDS, coalesced global
    {
      const unsigned short* base = xT + (size_t)((n*2 + ph)*H_IN) * (W_IN*64);
      #pragma unroll
      for (int it = 0; it < 3; ++it) {
        int li = it*512 + tid;          // < 1440 lane-loads of 16B
        if (li < 1440) {
          int chunk = li >> 3, sub = li & 7;
          int hh = chunk / 18, ww = chunk - hh*18;
          int hc = h0 + hh; if (hc > 111) hc = 111;
          int wc = w0 + ww; if (wc > 111) wc = 111;
          uint4 v = *(const uint4*)(base + ((size_t)hc*W_IN + wc)*64 + sub*8);
          *((uint4*)sm + li) = v;
        }
      }
    }
    __syncthreads();

    const unsigned short* Fp = F + ph*64;
    short8 aA[4], bA[4], aB[4], bB[4];

    auto LOADSTEP = [&](int st, short8* a, short8* b) {
      const int rs = st >> 1, ch = st & 1;
      const int r = rs / 3, s = rs - r*3;
      const int cb = ch*32 + lhi*8;
      const unsigned short* Frs = Fp + rs*(K_OUT*C_IN) + cb;
      #pragma unroll
      for (int mt = 0; mt < 4; ++mt)
        a[mt] = *(const short8*)(Frs + arow[mt]);
      const int key = ((wkey + s) & 7) << 3;
      const int off = (r*18 + s)*64 + (cb ^ key);
      #pragma unroll
      for (int nt = 0; nt < 4; ++nt)
        b[nt] = *(const short8*)&sm[browb[nt] + off];
    };
    auto MFMASTEP = [&](short8* a, short8* b) {
      #pragma unroll
      for (int mt = 0; mt < 4; ++mt)
        #pragma unroll
        for (int nt = 0; nt < 4; ++nt)
          acc[mt][nt] = __builtin_amdgcn_mfma_f32_16x16x32_bf16(a[mt], b[nt], acc[mt][nt], 0, 0, 0);
    };

    // 18 steps (9 rs x 2 c-chunks), software-pipelined 1 ahead, named dbuf regs
    LOADSTEP(0, aA, bA);
    #pragma unroll
    for (int st = 0; st < 18; st += 2) {
      LOADSTEP(st + 1, aB, bB);
      MFMASTEP(aA, bA);
      if (st + 2 < 18) LOADSTEP(st + 2, aA, bA);
      MFMASTEP(aB, bB);
    }
  }

  // epilogue: D frag: col(N=pixel)=l15, row(M=k)=lhi*4+reg
  const int wv = w0 + l15;
  #pragma unroll
  for (int nt = 0; nt < 4; ++nt) {
    int hv = h0 + wn*4 + nt;
    if (hv < H_OUTD && wv < W_OUTD) {
      float* po = out + (size_t)n*K_OUT*(H_OUTD*W_OUTD) + hv*W_OUTD + wv;
      #pragma unroll
      for (int mt = 0; mt < 4; ++mt) {
        #pragma unroll
        for (int reg = 0; reg < 4; ++reg) {
          int k = wm*64 + mt*16 + lhi*4 + reg;
          po[(size_t)k*(H_OUTD*W_OUTD)] = acc[mt][nt][reg];
        }
      }
    }
  }
}

// ---------------- fallback (ws too small): naive fp32 ----------------
__global__ void naive_conv(const float* __restrict__ x, const float* __restrict__ ft,
                           float* __restrict__ out) {
  int idx = blockIdx.x*256 + threadIdx.x;
  int total = NBATCH*K_OUT*H_OUTD*W_OUTD;
  if (idx >= total) return;
  int w = idx % W_OUTD; int t = idx / W_OUTD;
  int h = t % H_OUTD; t /= H_OUTD;
  int k = t % K_OUT; int nn = t / K_OUT;
  float acc = 0.f;
  for (int c = 0; c < C_IN; ++c)
    for (int r = 0; r < 3; ++r)
      for (int s = 0; s < 3; ++s)
        acc += x[((size_t)(nn*C_IN + c)*H_IN + h + r)*W_IN + w + s]
             * ft[((k*C_IN + c)*3 + r)*3 + s];
  out[idx] = acc;
}

extern "C" void kernel_launch(void* const* d_in, const int* in_sizes, int n_in,
                              void* d_out, int out_size, void* d_ws, size_t ws_size,
                              hipStream_t stream) {
  (void)in_sizes; (void)n_in; (void)out_size;
  const float* x  = (const float*)d_in[0];
  const float* ft = (const float*)d_in[1];
  float* out = (float*)d_out;
  size_t need = (size_t)(XT_ELEMS + F_ELEMS) * sizeof(unsigned short);
  if (ws_size >= need) {
    unsigned short* xT = (unsigned short*)d_ws;
    unsigned short* F  = xT + XT_ELEMS;
    xpose_kernel<<<dim3(112, 32), 256, 0, stream>>>(x, xT);
    fprep_kernel<<<dim3(1152), 256, 0, stream>>>(ft, F);
    conv_gemm<<<dim3(98, 32), 512, 0, stream>>>(xT, F, out);
  } else {
    int total = NBATCH*K_OUT*H_OUTD*W_OUTD;
    naive_conv<<<(total + 255)/256, 256, 0, stream>>>(x, ft, out);
  }
}

// Round 3
// 605.692 us; speedup vs baseline: 6.6315x; 6.6315x over previous
//
#include <hip/hip_runtime.h>

typedef short short8 __attribute__((ext_vector_type(8)));
typedef float f32x4 __attribute__((ext_vector_type(4)));
typedef unsigned int uint;

#define C_IN  128
#define H_IN  112
#define W_IN  112
#define K_OUT 256
#define H_OUTD 110
#define W_OUTD 110
#define NBATCH 32

// xT layout: [n][ph(2)][h(112)][w(112)][64] bf16, swizzled within 64: pos = (c&63) ^ ((w&7)<<3)
#define XT_ELEMS (NBATCH*2*H_IN*W_IN*64)   // 51,380,224
#define F_ELEMS  (9*K_OUT*C_IN)            // 294,912

__device__ __forceinline__ unsigned short f2bf(float f) {
  uint u = __float_as_uint(f);
  u += 0x7fffu + ((u >> 16) & 1u);   // RNE
  return (unsigned short)(u >> 16);
}

// ---------------- prep: x (NCHW f32) -> xT (swizzled bf16) ----------------
__global__ __launch_bounds__(256) void xpose_kernel(const float* __restrict__ x,
                                                    unsigned short* __restrict__ xT) {
  __shared__ unsigned short sm[H_IN * 128];   // [w][c''] 28,672 B
  const int n = blockIdx.y;
  const int h = blockIdx.x;
  const int tid = threadIdx.x;
  for (int it = 0; it < 28; ++it) {
    int idx = it*256 + tid;            // 0..7167  (64 c-pairs x 112 w)
    int w  = idx % 112;
    int cp = idx / 112;                // 0..63
    int c0 = cp*2;
    const float* px = x + ((size_t)(n*C_IN + c0)*H_IN + h)*W_IN + w;
    float f0 = px[0];
    float f1 = px[H_IN*W_IN];
    uint key  = ((uint)w & 7u) << 3;
    uint cpos = ((uint)c0 & 64u) | (((uint)c0 & 63u) ^ key);
    uint v = (uint)f2bf(f0) | ((uint)f2bf(f1) << 16);
    *(uint*)&sm[w*128 + cpos] = v;
  }
  __syncthreads();
  for (int it = 0; it < 7; ++it) {
    int idx = it*256 + tid;            // 0..1791
    int ph  = idx / 896;
    int rem = idx - ph*896;
    int w   = rem >> 3;
    int ck  = rem & 7;
    uint4 v = *(const uint4*)&sm[w*128 + ph*64 + ck*8];
    int off = (((n*2 + ph)*H_IN + h)*W_IN + w)*64 + ck*8;
    *(uint4*)&xT[off] = v;
  }
}

// ---- prep: filt (OIHW f32) -> F2 fragment-packed bf16 ----
// F2 chunk CH = (((rs*2+ph)*2+ch)*4 + wm)*4 + mt ; within chunk: [lane(64)][e(8)]
// element: k = wm*64+mt*16+(lane&15), c = ph*64+ch*32+(lane>>4)*8+e
__global__ __launch_bounds__(256) void fprep_kernel(const float* __restrict__ ft,
                                                    unsigned short* __restrict__ F) {
  int idx = blockIdx.x*256 + threadIdx.x;   // < 294912 = 9<<15
  int e    = idx & 7;
  int lane = (idx >> 3) & 63;
  int mt   = (idx >> 9) & 3;
  int wm   = (idx >> 11) & 3;
  int ch   = (idx >> 13) & 1;
  int ph   = (idx >> 14) & 1;
  int rs   = idx >> 15;
  int k = wm*64 + mt*16 + (lane & 15);
  int c = ph*64 + ch*32 + (lane >> 4)*8 + e;
  F[idx] = f2bf(ft[(k*C_IN + c)*9 + rs]);
}

// ---------------- main implicit-GEMM conv ----------------
// block: 512 thr (8 waves, 4M x 2N), output tile = 256 K_out x (8h x 16w) pixels
// LDS: halo tile 10h x 18w x 64c bf16 = 23,040 B
__global__ __launch_bounds__(512, 4) void conv_gemm(const unsigned short* __restrict__ xT,
                                                    const unsigned short* __restrict__ F,
                                                    float* __restrict__ out) {
  __shared__ unsigned short sm[10*18*64];   // 23,040 B
  const int tile = blockIdx.x;              // 0..97 (14 h-tiles x 7 w-tiles)
  const int n    = blockIdx.y;
  const int tid  = threadIdx.x;
  const int lane = tid & 63;
  const int wid  = tid >> 6;
  const int wm   = wid & 3;                 // M quadrant (64 k each)
  const int wn   = wid >> 2;                // N half (4 h-rows each)
  const int l15  = lane & 15;
  const int lhi  = lane >> 4;               // 0..3
  const int th   = tile / 7;
  const int tw   = tile - th*7;
  const int h0   = th*8;
  const int w0   = tw*16;

  const unsigned short* F2w = F + (wm*4)*512 + lane*8;  // per-wave fragment base

  int browb[4];
  #pragma unroll
  for (int nt = 0; nt < 4; ++nt)
    browb[nt] = ((wn*4 + nt)*18 + l15)*64;   // (hh row)*18 + ww(=l15), in shorts
  const int wkey = w0 + l15;

  f32x4 acc[4][4];
  #pragma unroll
  for (int mt = 0; mt < 4; ++mt)
    #pragma unroll
    for (int nt = 0; nt < 4; ++nt)
      acc[mt][nt] = (f32x4){0.f, 0.f, 0.f, 0.f};

  for (int ph = 0; ph < 2; ++ph) {
    if (ph) __syncthreads();
    // stage halo tile: 10x18 chunks of 128B, linear LDS, coalesced global
    {
      const unsigned short* base = xT + (size_t)((n*2 + ph)*H_IN) * (W_IN*64);
      #pragma unroll
      for (int it = 0; it < 3; ++it) {
        int li = it*512 + tid;          // < 1440 lane-loads of 16B
        if (li < 1440) {
          int chunk = li >> 3, sub = li & 7;
          int hh = chunk / 18, ww = chunk - hh*18;
          int hc = h0 + hh; if (hc > 111) hc = 111;
          int wc = w0 + ww; if (wc > 111) wc = 111;
          uint4 v = *(const uint4*)(base + ((size_t)hc*W_IN + wc)*64 + sub*8);
          *((uint4*)sm + li) = v;
        }
      }
    }
    __syncthreads();

    #pragma unroll
    for (int rs = 0; rs < 9; ++rs) {
      const int r = rs / 3, s = rs - r*3;
      const int key = ((wkey + s) & 7) << 3;
      #pragma unroll
      for (int ch = 0; ch < 2; ++ch) {
        // A: one fully-coalesced 1KB segment per load
        const unsigned short* Fs = F2w + (size_t)(((rs*2 + ph)*2 + ch)*16)*512;
        short8 a[4];
        #pragma unroll
        for (int mt = 0; mt < 4; ++mt)
          a[mt] = *(const short8*)(Fs + mt*512);
        // B: swizzled LDS, conflict-free
        const int cb = ch*32 + lhi*8;
        const int off = (r*18 + s)*64 + (cb ^ key);
        short8 b[4];
        #pragma unroll
        for (int nt = 0; nt < 4; ++nt)
          b[nt] = *(const short8*)&sm[browb[nt] + off];
        #pragma unroll
        for (int mt = 0; mt < 4; ++mt)
          #pragma unroll
          for (int nt = 0; nt < 4; ++nt)
            acc[mt][nt] = __builtin_amdgcn_mfma_f32_16x16x32_bf16(a[mt], b[nt], acc[mt][nt], 0, 0, 0);
      }
    }
  }

  // epilogue: D frag: col(N=pixel)=l15, row(M=k)=lhi*4+reg
  const int wv = w0 + l15;
  #pragma unroll
  for (int nt = 0; nt < 4; ++nt) {
    int hv = h0 + wn*4 + nt;
    if (hv < H_OUTD && wv < W_OUTD) {
      float* po = out + (size_t)n*K_OUT*(H_OUTD*W_OUTD) + hv*W_OUTD + wv;
      #pragma unroll
      for (int mt = 0; mt < 4; ++mt) {
        #pragma unroll
        for (int reg = 0; reg < 4; ++reg) {
          int k = wm*64 + mt*16 + lhi*4 + reg;
          po[(size_t)k*(H_OUTD*W_OUTD)] = acc[mt][nt][reg];
        }
      }
    }
  }
}

// ---------------- fallback (ws too small): naive fp32 ----------------
__global__ void naive_conv(const float* __restrict__ x, const float* __restrict__ ft,
                           float* __restrict__ out) {
  int idx = blockIdx.x*256 + threadIdx.x;
  int total = NBATCH*K_OUT*H_OUTD*W_OUTD;
  if (idx >= total) return;
  int w = idx % W_OUTD; int t = idx / W_OUTD;
  int h = t % H_OUTD; t /= H_OUTD;
  int k = t % K_OUT; int nn = t / K_OUT;
  float acc = 0.f;
  for (int c = 0; c < C_IN; ++c)
    for (int r = 0; r < 3; ++r)
      for (int s = 0; s < 3; ++s)
        acc += x[((size_t)(nn*C_IN + c)*H_IN + h + r)*W_IN + w + s]
             * ft[((k*C_IN + c)*3 + r)*3 + s];
  out[idx] = acc;
}

extern "C" void kernel_launch(void* const* d_in, const int* in_sizes, int n_in,
                              void* d_out, int out_size, void* d_ws, size_t ws_size,
                              hipStream_t stream) {
  (void)in_sizes; (void)n_in; (void)out_size;
  const float* x  = (const float*)d_in[0];
  const float* ft = (const float*)d_in[1];
  float* out = (float*)d_out;
  size_t need = (size_t)(XT_ELEMS + F_ELEMS) * sizeof(unsigned short);
  if (ws_size >= need) {
    unsigned short* xT = (unsigned short*)d_ws;
    unsigned short* F  = xT + XT_ELEMS;
    xpose_kernel<<<dim3(112, 32), 256, 0, stream>>>(x, xT);
    fprep_kernel<<<dim3(1152), 256, 0, stream>>>(ft, F);
    conv_gemm<<<dim3(98, 32), 512, 0, stream>>>(xT, F, out);
  } else {
    int total = NBATCH*K_OUT*H_OUTD*W_OUTD;
    naive_conv<<<(total + 255)/256, 256, 0, stream>>>(x, ft, out);
  }
}

// Round 4
// 408.748 us; speedup vs baseline: 9.8267x; 1.4818x over previous
//
#include <hip/hip_runtime.h>

typedef short short8 __attribute__((ext_vector_type(8)));
typedef float f32x4 __attribute__((ext_vector_type(4)));
typedef unsigned int uint;

#define C_IN  128
#define H_IN  112
#define W_IN  112
#define K_OUT 256
#define H_OUTD 110
#define W_OUTD 110
#define NBATCH 32

// xT layout: [n][h][w][cpos(128)] bf16, cpos = (c&64) | ((c&63) ^ ((w&7)<<3))
#define XT_ELEMS (NBATCH*H_IN*W_IN*128)    // 51,380,224
// F2 layout: [slice(36 = rs*4+ch)][wm(4)][mt(4)][lane(64)][e(8)]  (k=wm*64+mt*16+(lane&15), c=ch*32+(lane>>4)*8+e)
#define F_ELEMS  (36*4*4*64*8)             // 294,912

__device__ __forceinline__ unsigned short f2bf(float f) {
  uint u = __float_as_uint(f);
  u += 0x7fffu + ((u >> 16) & 1u);   // RNE
  return (unsigned short)(u >> 16);
}

__device__ __forceinline__ void gll16(const unsigned short* g, unsigned short* l) {
  __builtin_amdgcn_global_load_lds(
      (const __attribute__((address_space(1))) void*)g,
      (__attribute__((address_space(3))) void*)(uint)(uintptr_t)l, 16, 0, 0);
}

// ---------------- prep: x (NCHW f32) -> xT (swizzled bf16) ----------------
__global__ __launch_bounds__(256) void xpose_kernel(const float* __restrict__ x,
                                                    unsigned short* __restrict__ xT) {
  __shared__ unsigned short sm[H_IN * 128];   // [w][cpos] 28,672 B
  const int n = blockIdx.y;
  const int h = blockIdx.x;
  const int tid = threadIdx.x;
  for (int it = 0; it < 28; ++it) {
    int idx = it*256 + tid;            // 0..7167  (64 c-pairs x 112 w)
    int w  = idx % 112;
    int cp = idx / 112;                // 0..63
    int c0 = cp*2;
    const float* px = x + ((size_t)(n*C_IN + c0)*H_IN + h)*W_IN + w;
    float f0 = px[0];
    float f1 = px[H_IN*W_IN];
    uint key  = ((uint)w & 7u) << 3;
    uint cpos = ((uint)c0 & 64u) | (((uint)c0 & 63u) ^ key);
    uint v = (uint)f2bf(f0) | ((uint)f2bf(f1) << 16);
    *(uint*)&sm[w*128 + cpos] = v;
  }
  __syncthreads();
  for (int it = 0; it < 7; ++it) {
    int idx = it*256 + tid;            // 0..1791 chunks of 8 shorts
    int w  = idx >> 4;
    int cc = idx & 15;
    uint4 v = *(const uint4*)&sm[w*128 + cc*8];
    size_t off = (((size_t)n*H_IN + h)*W_IN + w)*128 + cc*8;
    *(uint4*)&xT[off] = v;
  }
}

// ---- prep: filt (OIHW f32) -> F2 fragment-packed bf16 (layout above) ----
__global__ __launch_bounds__(256) void fprep_kernel(const float* __restrict__ ft,
                                                    unsigned short* __restrict__ F) {
  int idx = blockIdx.x*256 + threadIdx.x;   // < 294912 = 9<<15
  int e    = idx & 7;
  int lane = (idx >> 3) & 63;
  int mt   = (idx >> 9) & 3;
  int wm   = (idx >> 11) & 3;
  int ch   = (idx >> 13) & 3;
  int rs   = idx >> 15;
  int k = wm*64 + mt*16 + (lane & 15);
  int c = ch*32 + (lane >> 4)*8 + e;
  F[idx] = f2bf(ft[(k*C_IN + c)*9 + rs]);
}

// ---------------- main implicit-GEMM conv ----------------
// block: 512 thr (8 waves, 4M x 2N), output tile = 256 K_out x (8h x 16w)
// LDS: x halo 10x18x128 (46,080 B, staged once) + F dbuf 2x16KB (32,768 B) = 78,848 B
__global__ __launch_bounds__(512, 4) void conv_gemm(const unsigned short* __restrict__ xT,
                                                    const unsigned short* __restrict__ F,
                                                    float* __restrict__ out) {
  __shared__ unsigned short smX[10*18*128];   // 23,040 elems
  __shared__ unsigned short smF[2*8192];      // 16,384 elems
  const int tile = blockIdx.x;                // 0..97 (14 h-tiles x 7 w-tiles)
  const int n    = blockIdx.y;
  const int tid  = threadIdx.x;
  const int lane = tid & 63;
  const int wid  = tid >> 6;
  const int wm   = wid & 3;                   // M quadrant (64 k each)
  const int wn   = wid >> 2;                  // N half (4 h-rows each)
  const int l15  = lane & 15;
  const int lhi  = lane >> 4;                 // 0..3
  const int th   = tile / 7;
  const int tw   = tile - th*7;
  const int h0   = th*8;
  const int w0   = tw*16;

  int browb[4];
  #pragma unroll
  for (int nt = 0; nt < 4; ++nt)
    browb[nt] = ((wn*4 + nt)*18 + l15)*128;   // (hh*18+ww)*128, in shorts
  const int wkey = w0 + l15;

  f32x4 acc[4][4];
  #pragma unroll
  for (int mt = 0; mt < 4; ++mt)
    #pragma unroll
    for (int nt = 0; nt < 4; ++nt)
      acc[mt][nt] = (f32x4){0.f, 0.f, 0.f, 0.f};

  // ---- prologue: stage x halo (2880 x 16B) + F slice 0, all async ----
  {
    const unsigned short* xbase = xT + (size_t)n*H_IN*W_IN*128;
    #pragma unroll
    for (int k = 0; k < 6; ++k) {
      int ci = k*512 + tid;
      if (ci < 2880) {
        int cell = ci >> 4, sub = ci & 15;
        int hh = cell / 18, ww = cell - hh*18;
        int hc = h0 + hh; if (hc > 111) hc = 111;
        int wc = w0 + ww; if (wc > 111) wc = 111;
        gll16(xbase + ((size_t)(hc*W_IN + wc))*128 + sub*8, &smX[ci*8]);
      }
    }
    gll16(F + tid*8, &smF[tid*8]);
    gll16(F + (512 + tid)*8, &smF[(512 + tid)*8]);
  }

  const unsigned short* Ftid = F + tid*8;

  #pragma unroll 2
  for (int i = 0; i < 36; ++i) {
    __syncthreads();                 // slice i (and x) landed; buf[(i+1)&1] free
    if (i + 1 < 36) {                // prefetch slice i+1 (consumed after next barrier)
      const unsigned short* src = Ftid + (i + 1)*8192;
      unsigned short* dst = &smF[((i + 1) & 1)*8192] + tid*8;
      gll16(src, dst);
      gll16(src + 4096, dst + 4096);
    }
    const int rs = i >> 2, ch = i & 3;
    const int r = rs/3, s = rs - r*3;
    const int key  = ((wkey + s) & 7) << 3;
    const int cb   = ch*32 + lhi*8;
    const int cpos = (cb & 64) | ((cb & 63) ^ key);
    const int off  = (r*18 + s)*128 + cpos;
    short8 b[4];
    #pragma unroll
    for (int nt = 0; nt < 4; ++nt)
      b[nt] = *(const short8*)&smX[browb[nt] + off];
    const unsigned short* As = smF + (i & 1)*8192 + wm*2048 + lane*8;
    #pragma unroll
    for (int mt = 0; mt < 4; ++mt) {
      short8 a = *(const short8*)(As + mt*512);
      #pragma unroll
      for (int nt = 0; nt < 4; ++nt)
        acc[mt][nt] = __builtin_amdgcn_mfma_f32_16x16x32_bf16(a, b[nt], acc[mt][nt], 0, 0, 0);
    }
  }

  // epilogue: D frag: col(N=pixel)=l15, row(M=k)=lhi*4+reg
  const int wv = w0 + l15;
  #pragma unroll
  for (int nt = 0; nt < 4; ++nt) {
    int hv = h0 + wn*4 + nt;
    if (hv < H_OUTD && wv < W_OUTD) {
      float* po = out + (size_t)n*K_OUT*(H_OUTD*W_OUTD) + hv*W_OUTD + wv;
      #pragma unroll
      for (int mt = 0; mt < 4; ++mt) {
        #pragma unroll
        for (int reg = 0; reg < 4; ++reg) {
          int k = wm*64 + mt*16 + lhi*4 + reg;
          po[(size_t)k*(H_OUTD*W_OUTD)] = acc[mt][nt][reg];
        }
      }
    }
  }
}

// ---------------- fallback (ws too small): naive fp32 ----------------
__global__ void naive_conv(const float* __restrict__ x, const float* __restrict__ ft,
                           float* __restrict__ out) {
  int idx = blockIdx.x*256 + threadIdx.x;
  int total = NBATCH*K_OUT*H_OUTD*W_OUTD;
  if (idx >= total) return;
  int w = idx % W_OUTD; int t = idx / W_OUTD;
  int h = t % H_OUTD; t /= H_OUTD;
  int k = t % K_OUT; int nn = t / K_OUT;
  float acc = 0.f;
  for (int c = 0; c < C_IN; ++c)
    for (int r = 0; r < 3; ++r)
      for (int s = 0; s < 3; ++s)
        acc += x[((size_t)(nn*C_IN + c)*H_IN + h + r)*W_IN + w + s]
             * ft[((k*C_IN + c)*3 + r)*3 + s];
  out[idx] = acc;
}

extern "C" void kernel_launch(void* const* d_in, const int* in_sizes, int n_in,
                              void* d_out, int out_size, void* d_ws, size_t ws_size,
                              hipStream_t stream) {
  (void)in_sizes; (void)n_in; (void)out_size;
  const float* x  = (const float*)d_in[0];
  const float* ft = (const float*)d_in[1];
  float* out = (float*)d_out;
  size_t need = (size_t)(XT_ELEMS + F_ELEMS) * sizeof(unsigned short);
  if (ws_size >= need) {
    unsigned short* xT = (unsigned short*)d_ws;
    unsigned short* F  = xT + XT_ELEMS;
    xpose_kernel<<<dim3(112, 32), 256, 0, stream>>>(x, xT);
    fprep_kernel<<<dim3(1152), 256, 0, stream>>>(ft, F);
    conv_gemm<<<dim3(98, 32), 512, 0, stream>>>(xT, F, out);
  } else {
    int total = NBATCH*K_OUT*H_OUTD*W_OUTD;
    naive_conv<<<(total + 255)/256, 256, 0, stream>>>(x, ft, out);
  }
}

// Round 5
// 359.893 us; speedup vs baseline: 11.1607x; 1.1357x over previous
//
#include <hip/hip_runtime.h>

typedef short short8 __attribute__((ext_vector_type(8)));
typedef float f32x4 __attribute__((ext_vector_type(4)));
typedef unsigned int uint;

#define C_IN  128
#define H_IN  112
#define W_IN  112
#define K_OUT 256
#define H_OUTD 110
#define W_OUTD 110
#define NBATCH 32

// xT layout: [n][h][w][cpos(128)] bf16, cpos = (c&64) | ((c&63) ^ ((w&7)<<3))
#define XT_ELEMS (NBATCH*H_IN*W_IN*128)    // 51,380,224
// F2 layout: [slice(36 = rs*4+ch)][wm(4)][mt(4)][lane(64)][e(8)]
//            k = wm*64+mt*16+(lane&15), c = ch*32+(lane>>4)*8+e
#define F_ELEMS  (36*4*4*64*8)             // 294,912

__device__ __forceinline__ unsigned short f2bf(float f) {
  uint u = __float_as_uint(f);
  u += 0x7fffu + ((u >> 16) & 1u);   // RNE
  return (unsigned short)(u >> 16);
}

__device__ __forceinline__ void gll16(const unsigned short* g, unsigned short* l) {
  __builtin_amdgcn_global_load_lds(
      (const __attribute__((address_space(1))) void*)g,
      (__attribute__((address_space(3))) void*)(uint)(uintptr_t)l, 16, 0, 0);
}

// ---------------- prep: x (NCHW f32) -> xT (swizzled bf16) ----------------
__global__ __launch_bounds__(256) void xpose_kernel(const float* __restrict__ x,
                                                    unsigned short* __restrict__ xT) {
  __shared__ unsigned short sm[H_IN * 128];   // [w][cpos] 28,672 B
  const int n = blockIdx.y;
  const int h = blockIdx.x;
  const int tid = threadIdx.x;
  for (int it = 0; it < 28; ++it) {
    int idx = it*256 + tid;            // 0..7167  (64 c-pairs x 112 w)
    int w  = idx % 112;
    int cp = idx / 112;                // 0..63
    int c0 = cp*2;
    const float* px = x + ((size_t)(n*C_IN + c0)*H_IN + h)*W_IN + w;
    float f0 = px[0];
    float f1 = px[H_IN*W_IN];
    uint key  = ((uint)w & 7u) << 3;
    uint cpos = ((uint)c0 & 64u) | (((uint)c0 & 63u) ^ key);
    uint v = (uint)f2bf(f0) | ((uint)f2bf(f1) << 16);
    *(uint*)&sm[w*128 + cpos] = v;
  }
  __syncthreads();
  for (int it = 0; it < 7; ++it) {
    int idx = it*256 + tid;            // 0..1791 chunks of 8 shorts
    int w  = idx >> 4;
    int cc = idx & 15;
    uint4 v = *(const uint4*)&sm[w*128 + cc*8];
    size_t off = (((size_t)n*H_IN + h)*W_IN + w)*128 + cc*8;
    *(uint4*)&xT[off] = v;
  }
}

// ---- prep: filt (OIHW f32) -> F2 fragment-packed bf16 (layout above) ----
__global__ __launch_bounds__(256) void fprep_kernel(const float* __restrict__ ft,
                                                    unsigned short* __restrict__ F) {
  int idx = blockIdx.x*256 + threadIdx.x;   // < 294912 = 9<<15
  int e    = idx & 7;
  int lane = (idx >> 3) & 63;
  int mt   = (idx >> 9) & 3;
  int wm   = (idx >> 11) & 3;
  int ch   = (idx >> 13) & 3;
  int rs   = idx >> 15;
  int k = wm*64 + mt*16 + (lane & 15);
  int c = ch*32 + (lane >> 4)*8 + e;
  F[idx] = f2bf(ft[(k*C_IN + c)*9 + rs]);
}

// ---------------- main implicit-GEMM conv ----------------
// block: 512 thr (8 waves, 4M x 2N), output tile = 256 K_out x (8h x 16w)
// LDS: x halo 10x18x128 bf16 = 46,080 B, staged ONCE. No barriers in K-loop.
// A-fragments: global->reg, 1-step-ahead named double buffer (F is L2-resident).
__global__ __launch_bounds__(512, 4) void conv_gemm(const unsigned short* __restrict__ xT,
                                                    const unsigned short* __restrict__ F,
                                                    float* __restrict__ out) {
  __shared__ unsigned short smX[10*18*128];   // 46,080 B
  // bijective XCD swizzle: 3136 blocks = 8 XCDs x 392
  const int bid  = blockIdx.y*98 + blockIdx.x;
  const int wgid = (bid & 7)*392 + (bid >> 3);
  const int tile = wgid % 98;                 // 14 h-tiles x 7 w-tiles
  const int n    = wgid / 98;
  const int tid  = threadIdx.x;
  const int lane = tid & 63;
  const int wid  = tid >> 6;
  const int wm   = wid & 3;                   // M quadrant (64 k each)
  const int wn   = wid >> 2;                  // N half (4 h-rows each)
  const int l15  = lane & 15;
  const int lhi  = lane >> 4;                 // 0..3
  const int th   = tile / 7;
  const int tw   = tile - th*7;
  const int h0   = th*8;
  const int w0   = tw*16;

  int browb[4];
  #pragma unroll
  for (int nt = 0; nt < 4; ++nt)
    browb[nt] = ((wn*4 + nt)*18 + l15)*128;   // (hh*18+ww)*128, in shorts
  const int wkey = w0 + l15;

  f32x4 acc[4][4];
  #pragma unroll
  for (int mt = 0; mt < 4; ++mt)
    #pragma unroll
    for (int nt = 0; nt < 4; ++nt)
      acc[mt][nt] = (f32x4){0.f, 0.f, 0.f, 0.f};

  // per-wave A base: F + ((wm*4 + mt)*64 + lane)*8 ; slice stride 8192 shorts
  const unsigned short* Aw = F + wm*2048 + lane*8;

  // prefetch A slice 0 (overlaps with halo staging)
  short8 aA[4], aB[4];
  #pragma unroll
  for (int mt = 0; mt < 4; ++mt)
    aA[mt] = *(const short8*)(Aw + mt*512);

  // stage x halo (2880 x 16B chunks = 45 full waves), async direct-to-LDS
  {
    const unsigned short* xbase = xT + (size_t)n*H_IN*W_IN*128;
    #pragma unroll
    for (int k = 0; k < 6; ++k) {
      int ci = k*512 + tid;
      if (ci < 2880) {
        int cell = ci >> 4, sub = ci & 15;
        int hh = cell / 18, ww = cell - hh*18;
        int hc = h0 + hh; if (hc > 111) hc = 111;
        int wc = w0 + ww; if (wc > 111) wc = 111;
        gll16(xbase + ((size_t)(hc*W_IN + wc))*128 + sub*8, &smX[ci*8]);
      }
    }
  }
  __syncthreads();   // only barrier in the kernel (drains gll16 queue)

  for (int i = 0; i < 36; i += 2) {
    // issue A for step i+1
    {
      const unsigned short* As = Aw + (size_t)(i + 1)*8192;
      #pragma unroll
      for (int mt = 0; mt < 4; ++mt)
        aB[mt] = *(const short8*)(As + mt*512);
    }
    // compute step i with aA
    {
      const int rs = i >> 2, ch = i & 3;
      const int r = rs/3, s = rs - r*3;
      const int key  = ((wkey + s) & 7) << 3;
      const int cb   = ch*32 + lhi*8;
      const int cpos = (cb & 64) | ((cb & 63) ^ key);
      const int off  = (r*18 + s)*128 + cpos;
      #pragma unroll
      for (int nt = 0; nt < 4; ++nt) {
        short8 b = *(const short8*)&smX[browb[nt] + off];
        #pragma unroll
        for (int mt = 0; mt < 4; ++mt)
          acc[mt][nt] = __builtin_amdgcn_mfma_f32_16x16x32_bf16(aA[mt], b, acc[mt][nt], 0, 0, 0);
      }
    }
    // issue A for step i+2
    if (i + 2 < 36) {
      const unsigned short* As = Aw + (size_t)(i + 2)*8192;
      #pragma unroll
      for (int mt = 0; mt < 4; ++mt)
        aA[mt] = *(const short8*)(As + mt*512);
    }
    // compute step i+1 with aB
    {
      const int j = i + 1;
      const int rs = j >> 2, ch = j & 3;
      const int r = rs/3, s = rs - r*3;
      const int key  = ((wkey + s) & 7) << 3;
      const int cb   = ch*32 + lhi*8;
      const int cpos = (cb & 64) | ((cb & 63) ^ key);
      const int off  = (r*18 + s)*128 + cpos;
      #pragma unroll
      for (int nt = 0; nt < 4; ++nt) {
        short8 b = *(const short8*)&smX[browb[nt] + off];
        #pragma unroll
        for (int mt = 0; mt < 4; ++mt)
          acc[mt][nt] = __builtin_amdgcn_mfma_f32_16x16x32_bf16(aB[mt], b, acc[mt][nt], 0, 0, 0);
      }
    }
  }

  // epilogue: D frag: col(N=pixel)=l15, row(M=k)=lhi*4+reg
  const int wv = w0 + l15;
  #pragma unroll
  for (int nt = 0; nt < 4; ++nt) {
    int hv = h0 + wn*4 + nt;
    if (hv < H_OUTD && wv < W_OUTD) {
      float* po = out + (size_t)n*K_OUT*(H_OUTD*W_OUTD) + hv*W_OUTD + wv;
      #pragma unroll
      for (int mt = 0; mt < 4; ++mt) {
        #pragma unroll
        for (int reg = 0; reg < 4; ++reg) {
          int k = wm*64 + mt*16 + lhi*4 + reg;
          po[(size_t)k*(H_OUTD*W_OUTD)] = acc[mt][nt][reg];
        }
      }
    }
  }
}

// ---------------- fallback (ws too small): naive fp32 ----------------
__global__ void naive_conv(const float* __restrict__ x, const float* __restrict__ ft,
                           float* __restrict__ out) {
  int idx = blockIdx.x*256 + threadIdx.x;
  int total = NBATCH*K_OUT*H_OUTD*W_OUTD;
  if (idx >= total) return;
  int w = idx % W_OUTD; int t = idx / W_OUTD;
  int h = t % H_OUTD; t /= H_OUTD;
  int k = t % K_OUT; int nn = t / K_OUT;
  float acc = 0.f;
  for (int c = 0; c < C_IN; ++c)
    for (int r = 0; r < 3; ++r)
      for (int s = 0; s < 3; ++s)
        acc += x[((size_t)(nn*C_IN + c)*H_IN + h + r)*W_IN + w + s]
             * ft[((k*C_IN + c)*3 + r)*3 + s];
  out[idx] = acc;
}

extern "C" void kernel_launch(void* const* d_in, const int* in_sizes, int n_in,
                              void* d_out, int out_size, void* d_ws, size_t ws_size,
                              hipStream_t stream) {
  (void)in_sizes; (void)n_in; (void)out_size;
  const float* x  = (const float*)d_in[0];
  const float* ft = (const float*)d_in[1];
  float* out = (float*)d_out;
  size_t need = (size_t)(XT_ELEMS + F_ELEMS) * sizeof(unsigned short);
  if (ws_size >= need) {
    unsigned short* xT = (unsigned short*)d_ws;
    unsigned short* F  = xT + XT_ELEMS;
    xpose_kernel<<<dim3(112, 32), 256, 0, stream>>>(x, xT);
    fprep_kernel<<<dim3(1152), 256, 0, stream>>>(ft, F);
    conv_gemm<<<dim3(98, 32), 512, 0, stream>>>(xT, F, out);
  } else {
    int total = NBATCH*K_OUT*H_OUTD*W_OUTD;
    naive_conv<<<(total + 255)/256, 256, 0, stream>>>(x, ft, out);
  }
}